// Round 1
// baseline (1171.029 us; speedup 1.0000x reference)
//
#include <hip/hip_runtime.h>

// 4-layer LSTM (B=1024,T=512,H=64,G=256) + FC head, fully fused persistent kernel.
// 256 blocks x 256 threads: block = (layer = bid&3, 16-row batch chunk).
// Layers pipelined via agent-scope atomic ring buffer in d_ws (poison-safe: 0xAA.. < 0).
// bf16 MFMA 16x16x32, fp32 accum; c-state in registers; h via double-buffered swizzled LDS.

#define TLEN   512
#define BATCH  1024
#define HDIM   64
#define NCHUNK 64
#define SPIN_CAP 5000000
#define AG __HIP_MEMORY_SCOPE_AGENT

typedef __bf16 bf16x8 __attribute__((ext_vector_type(8)));
typedef float  f32x4  __attribute__((ext_vector_type(4)));

struct Params {
  const float* x;
  const float* wih[4];
  const float* whh[4];
  const float* bih[4];
  const float* bhh[4];
  const float* fc1w; const float* fc1b;
  const float* fc2w; const float* fc2b;
  float* out;
  char* ws;
  int R; int Rmask; int cstep;
};

__device__ __forceinline__ bf16x8 bfzero() {
  union { unsigned long long u[2]; bf16x8 v; } z; z.u[0] = 0ull; z.u[1] = 0ull; return z.v;
}
__device__ __forceinline__ float fast_sigmoid(float x) {
  return __builtin_amdgcn_rcpf(1.f + __expf(-x));
}
__device__ __forceinline__ float fast_tanh(float x) {
  float e = __expf(2.f * x);
  return 1.f - 2.f * __builtin_amdgcn_rcpf(e + 1.f);
}

__global__ __launch_bounds__(256, 1) void lstm_pipe(Params p)
{
  const int bid  = blockIdx.x;
  const int L    = bid & 3;          // layer
  const int chunk = bid >> 2;        // batch chunk (16 rows)
  const int b0   = chunk * 16;
  const int tid  = threadIdx.x;
  const int w    = tid >> 6;         // wave 0..3 -> columns [16w,16w+16) of each gate
  const int lane = tid & 63;
  const int quad = lane >> 4;
  const int l15  = lane & 15;

  __shared__ __bf16 h_lds[2 * 16 * 64];   // double-buffered h tile, XOR-swizzled
  __shared__ float  s_fc1w[32 * 64];
  __shared__ float  s_z[16 * 32];
  __shared__ float  s_fc1b[32];
  __shared__ float  s_fc2w[96];
  __shared__ float  s_fc2b[3];

  int* prodcnt = (int*)p.ws;                      // [(Lb*64+chunk)*4+wave]*16 (64B stride)
  int* ackcnt  = (int*)(p.ws + 48 * 1024);        // [(Lb*64+chunk)]*16
  unsigned short* hbuf = (unsigned short*)(p.ws + 64 * 1024); // ring: [(Lb*R+slot)*1024+b]*64+k
  const int R = p.R;

  // ---- stage weight fragments into registers (bf16) ----
  bf16x8 whhf[4][2];
  bf16x8 wihf[4][2];
  float  bias[4];
  {
    const float* whh = p.whh[L];
    const float* wih = p.wih[L];
    const float* bih = p.bih[L];
    const float* bhh = p.bhh[L];
#pragma unroll
    for (int g = 0; g < 4; g++) {
      int n = g * 64 + w * 16 + l15;  // B-frag: lane&15 = n, k = 32q + quad*8 + j
      bias[g] = bih[n] + bhh[n];
#pragma unroll
      for (int q = 0; q < 2; q++) {
        const float* s = whh + n * 64 + q * 32 + quad * 8;
        bf16x8 f;
#pragma unroll
        for (int j = 0; j < 8; j++) f[j] = (__bf16)s[j];
        whhf[g][q] = f;
      }
      if (L == 0) {                   // w_ih_0 is (256,4): pad K to 32 with zeros
        bf16x8 f = bfzero();
        if (quad == 0) {
#pragma unroll
          for (int j = 0; j < 4; j++) f[j] = (__bf16)wih[n * 4 + j];
        }
        wihf[g][0] = f; wihf[g][1] = f;
      } else {
#pragma unroll
        for (int q = 0; q < 2; q++) {
          const float* s = wih + n * 64 + q * 32 + quad * 8;
          bf16x8 f;
#pragma unroll
          for (int j = 0; j < 8; j++) f[j] = (__bf16)s[j];
          wihf[g][q] = f;
        }
      }
    }
  }

  { // zero h buffer 0 (t=0 reads zeros)
    int* hi = (int*)h_lds;
    for (int i = tid; i < 512; i += 256) hi[i] = 0;
  }
  float cst[4] = {0.f, 0.f, 0.f, 0.f};

  // counter indices (producer: per-wave release; consumer: per-lane poll of the 2 source waves)
  const int wa    = quad >> 1;
  const int ia    = (L > 0) ? ((((L - 1) * NCHUNK + chunk) * 4 + wa) * 16) : 0;
  const int ib    = (L > 0) ? ((((L - 1) * NCHUNK + chunk) * 4 + 2 + wa) * 16) : 0;
  const int ackrd = ((L - 1) * NCHUNK + chunk) * 16;
  const int pidx  = ((L * NCHUNK + chunk) * 4 + w) * 16;
  const int ackwr = (L * NCHUNK + chunk) * 16;

  __syncthreads();

  // ---- prologue: input fragment for t=0 ----
  bf16x8 xfc[2]; xfc[0] = bfzero(); xfc[1] = bfzero();
  if (L == 0) {
    if (quad == 0) {
      const float4 xv = *(const float4*)(p.x + ((size_t)(b0 + l15) * TLEN + 0) * 4);
      bf16x8 f = bfzero();
      f[0] = (__bf16)xv.x; f[1] = (__bf16)xv.y; f[2] = (__bf16)xv.z; f[3] = (__bf16)xv.w;
      xfc[0] = f;
    }
  } else {
    int spins = 0;
    while (__hip_atomic_load(&prodcnt[ia], __ATOMIC_RELAXED, AG) < 1) {
      if (++spins > SPIN_CAP) break; __builtin_amdgcn_s_sleep(1);
    }
    spins = 0;
    while (__hip_atomic_load(&prodcnt[ib], __ATOMIC_RELAXED, AG) < 1) {
      if (++spins > SPIN_CAP) break; __builtin_amdgcn_s_sleep(1);
    }
    __asm__ volatile("" ::: "memory");
    unsigned short* sbase = hbuf + ((size_t)((L - 1) * R + 0) * BATCH + b0 + l15) * 64;
#pragma unroll
    for (int q = 0; q < 2; q++) {
      union { bf16x8 v; unsigned long long u[2]; } cv;
      unsigned long long* s64 = (unsigned long long*)(sbase + 32 * q + quad * 8);
      cv.u[0] = __hip_atomic_load(&s64[0], __ATOMIC_RELAXED, AG);
      cv.u[1] = __hip_atomic_load(&s64[1], __ATOMIC_RELAXED, AG);
      xfc[q] = cv.v;
    }
  }

  int lastack = 0;

  for (int t = 0; t < TLEN; t++) {
    const int rb = t & 1;
    const int wb = rb ^ 1;
    const int slot = t & p.Rmask;

    // h fragments from LDS (A-frag: lane&15=m, k=32q+quad*8+j; XOR-swizzled 16B groups)
    bf16x8 hf[2];
#pragma unroll
    for (int q = 0; q < 2; q++) {
      int sg = (4 * q + quad) ^ (l15 & 7);
      hf[q] = *(const bf16x8*)&h_lds[rb * 1024 + l15 * 64 + sg * 8];
    }

    // gates = bias + x@Wih^T + h@Whh^T   (fp32 accum)
    f32x4 acc[4];
#pragma unroll
    for (int g = 0; g < 4; g++) { f32x4 a = {bias[g], bias[g], bias[g], bias[g]}; acc[g] = a; }
    if (L == 0) {
#pragma unroll
      for (int g = 0; g < 4; g++)
        acc[g] = __builtin_amdgcn_mfma_f32_16x16x32_bf16(xfc[0], wihf[g][0], acc[g], 0, 0, 0);
    } else {
#pragma unroll
      for (int g = 0; g < 4; g++)
#pragma unroll
        for (int q = 0; q < 2; q++)
          acc[g] = __builtin_amdgcn_mfma_f32_16x16x32_bf16(xfc[q], wihf[g][q], acc[g], 0, 0, 0);
    }
#pragma unroll
    for (int g = 0; g < 4; g++)
#pragma unroll
      for (int q = 0; q < 2; q++)
        acc[g] = __builtin_amdgcn_mfma_f32_16x16x32_bf16(hf[q], whhf[g][q], acc[g], 0, 0, 0);

    // prefetch next step's input while MFMAs are in flight
    bf16x8 xfn[2]; xfn[0] = xfc[0]; xfn[1] = xfc[1];
    if (t + 1 < TLEN) {
      if (L == 0) {
        if (quad == 0) {
          const float4 xv = *(const float4*)(p.x + ((size_t)(b0 + l15) * TLEN + (t + 1)) * 4);
          bf16x8 f = bfzero();
          f[0] = (__bf16)xv.x; f[1] = (__bf16)xv.y; f[2] = (__bf16)xv.z; f[3] = (__bf16)xv.w;
          xfn[0] = f;
        }
      } else {
        const int need = t + 2;
        int spins = 0;
        while (__hip_atomic_load(&prodcnt[ia], __ATOMIC_RELAXED, AG) < need) {
          if (++spins > SPIN_CAP) break; __builtin_amdgcn_s_sleep(1);
        }
        spins = 0;
        while (__hip_atomic_load(&prodcnt[ib], __ATOMIC_RELAXED, AG) < need) {
          if (++spins > SPIN_CAP) break; __builtin_amdgcn_s_sleep(1);
        }
        __asm__ volatile("" ::: "memory");
        const int nslot = (t + 1) & p.Rmask;
        unsigned short* sbase = hbuf + ((size_t)((L - 1) * R + nslot) * BATCH + b0 + l15) * 64;
#pragma unroll
        for (int q = 0; q < 2; q++) {
          union { bf16x8 v; unsigned long long u[2]; } cv;
          unsigned long long* s64 = (unsigned long long*)(sbase + 32 * q + quad * 8);
          cv.u[0] = __hip_atomic_load(&s64[0], __ATOMIC_RELAXED, AG);
          cv.u[1] = __hip_atomic_load(&s64[1], __ATOMIC_RELAXED, AG);
          xfn[q] = cv.v;
        }
      }
    }

    // per-lane LSTM cell: lane holds (m=quad*4+r, col=w*16+l15) for all 4 gates
    __bf16 hv[4];
    unsigned short hbits[4];
#pragma unroll
    for (int r = 0; r < 4; r++) {
      float ig = fast_sigmoid(acc[0][r]);
      float fg = fast_sigmoid(acc[1][r]);
      float gg = fast_tanh(acc[2][r]);
      float og = fast_sigmoid(acc[3][r]);
      float c = fg * cst[r] + ig * gg;
      cst[r] = c;
      float h = og * fast_tanh(c);
      __bf16 hb = (__bf16)h;
      hv[r] = hb;
      union { __bf16 b; unsigned short s; } cv2; cv2.b = hb;
      hbits[r] = cv2.s;
    }

    // producer: publish h_t (agent-coherent u32 stores, col pairs packed via shfl)
    if (L < 3) {
      if ((t & (p.cstep - 1)) == 0 && t >= p.cstep) {   // lazy ring backpressure
        if (lastack + R < t + p.cstep) {
          int spins = 0;
          while (true) {
            int a = __hip_atomic_load(&ackcnt[ackwr], __ATOMIC_RELAXED, AG);
            if (a < 0) a = 0;                           // 0xAA poison is negative
            if (a + R >= t + p.cstep) { lastack = a; break; }
            if (++spins > SPIN_CAP) break;
            __builtin_amdgcn_s_sleep(1);
          }
        }
      }
      const int col = w * 16 + l15;
      unsigned* h32 = (unsigned*)(hbuf + (size_t)(L * R + slot) * BATCH * 64);
#pragma unroll
      for (int r = 0; r < 4; r++) {
        unsigned v = hbits[r];
        unsigned o = (unsigned)__shfl_xor((int)v, 1);
        if ((lane & 1) == 0) {
          int m = quad * 4 + r;
          int idx = ((b0 + m) * 64 + col) >> 1;
          __hip_atomic_store(&h32[idx], v | (o << 16), __ATOMIC_RELAXED, AG);
        }
      }
    }

    // h -> LDS (swizzled), into the write buffer
    {
      const int col = w * 16 + l15;
      const int g0 = col >> 3;
#pragma unroll
      for (int r = 0; r < 4; r++) {
        int m = quad * 4 + r;
        int sg = g0 ^ (m & 7);
        h_lds[wb * 1024 + m * 64 + sg * 8 + (col & 7)] = hv[r];
      }
    }

    __syncthreads();  // drains vmcnt (h stores coherent) + lgkm; one barrier per step

    if (L < 3 && lane == 0)
      __hip_atomic_store(&prodcnt[pidx], t + 1, __ATOMIC_RELAXED, AG);
    if (L > 0 && tid == 0)
      __hip_atomic_store(&ackcnt[ackrd], t + 1, __ATOMIC_RELAXED, AG);

    xfc[0] = xfn[0]; xfc[1] = xfn[1];
  }

  // ---- FC head + softmax, fused into layer-3 blocks (final h is in buffer 0) ----
  if (L == 3) {
    for (int i = tid; i < 2048; i += 256) s_fc1w[i] = p.fc1w[i];
    if (tid < 32) s_fc1b[tid] = p.fc1b[tid];
    if (tid < 96) s_fc2w[tid] = p.fc2w[tid];
    if (tid < 3)  s_fc2b[tid] = p.fc2b[tid];
    __syncthreads();
    for (int pi = tid; pi < 512; pi += 256) {
      int m = pi >> 5, u = pi & 31;
      float s = s_fc1b[u];
      const float* wrow = &s_fc1w[u * 64];
#pragma unroll
      for (int k = 0; k < 64; k++) {
        int sg = (k >> 3) ^ (m & 7);
        s += (float)h_lds[m * 64 + sg * 8 + (k & 7)] * wrow[k];
      }
      s_z[m * 32 + u] = fmaxf(s, 0.f);
    }
    __syncthreads();
    if (tid < 16) {
      int m = tid;
      float lg[3];
#pragma unroll
      for (int v = 0; v < 3; v++) {
        float s = s_fc2b[v];
#pragma unroll
        for (int u = 0; u < 32; u++) s += s_z[m * 32 + u] * s_fc2w[v * 32 + u];
        lg[v] = s;
      }
      float mx = fmaxf(lg[0], fmaxf(lg[1], lg[2]));
      float e0 = __expf(lg[0] - mx), e1 = __expf(lg[1] - mx), e2 = __expf(lg[2] - mx);
      float inv = 1.f / (e0 + e1 + e2);
      float* o = p.out + (size_t)(b0 + m) * 3;
      o[0] = e0 * inv; o[1] = e1 * inv; o[2] = e2 * inv;
    }
  }
}

extern "C" void kernel_launch(void* const* d_in, const int* in_sizes, int n_in,
                              void* d_out, int out_size, void* d_ws, size_t ws_size,
                              hipStream_t stream)
{
  (void)in_sizes; (void)n_in; (void)out_size;
  Params p;
  p.x = (const float*)d_in[0];
  for (int l = 0; l < 4; l++) {
    p.wih[l] = (const float*)d_in[1 + 4 * l];
    p.whh[l] = (const float*)d_in[2 + 4 * l];
    p.bih[l] = (const float*)d_in[3 + 4 * l];
    p.bhh[l] = (const float*)d_in[4 + 4 * l];
  }
  p.fc1w = (const float*)d_in[17];
  p.fc1b = (const float*)d_in[18];
  p.fc2w = (const float*)d_in[19];
  p.fc2b = (const float*)d_in[20];
  p.out = (float*)d_out;
  p.ws  = (char*)d_ws;

  // ring size: largest power-of-2 slots fitting in ws (64KB reserved for counters)
  const size_t slotbytes = 3ull * BATCH * HDIM * sizeof(unsigned short); // 384 KB per slot-set
  const size_t avail = (ws_size > 65536) ? (ws_size - 65536) : 0;
  int R = 2;
  while (R < 64 && (size_t)(R * 2) * slotbytes <= avail) R <<= 1;
  p.R = R; p.Rmask = R - 1;
  p.cstep = (R >= 64) ? 32 : ((R >= 4) ? (R / 2) : 1);

  hipLaunchKernelGGL(lstm_pipe, dim3(256), dim3(256), 0, stream, p);
}